// Round 5
// baseline (204.991 us; speedup 1.0000x reference)
//
#include <hip/hip_runtime.h>
#include <math.h>

#define NSAMPLE 32
constexpr int B_ = 2, N_ = 8192, C_ = 64, C1_ = 128, C2_ = 128, CIN_ = 67;
constexpr int KP = 96;            // padded Cin for GEMM1 (3 k-steps of 32)
constexpr float BQ_R2 = 0.15f * 0.15f;
constexpr float EPS_ = 1e-5f;

typedef __attribute__((ext_vector_type(8))) short bf16x8;   // 8 bf16 = 4 VGPR
typedef __attribute__((ext_vector_type(4))) float f32x4;
typedef unsigned long long ull;

__device__ __forceinline__ short f2bf(float x) {            // RNE (cold paths)
    union { float f; unsigned u; } v; v.f = x;
    return (short)((v.u + 0x7FFFu + ((v.u >> 16) & 1u)) >> 16);
}
__device__ __forceinline__ unsigned cvt_pk_bf16(float a, float b) {
    unsigned r;                    // low16 = bf16(a), high16 = bf16(b), HW RNE
    asm("v_cvt_pk_bf16_f32 %0, %1, %2" : "=v"(r) : "v"(a), "v"(b));
    return r;
}

// ---- prep+query: blocks [0,64): transpose f -> fT bf16 [B*N][64]
//      block 64: weight/BN prep
//      blocks [65, 65+4096): ball query (wave/point, 256 cand/iter, prefetched)
constexpr int TBLK = (B_ * N_) / 256;        // 64
constexpr int QBLK0 = TBLK + 1;              // 65

__global__ __launch_bounds__(256) void prep_query_kernel(
    const float* __restrict__ p, const float* __restrict__ f,
    short* __restrict__ fT, int* __restrict__ idx, short* __restrict__ dpq,
    const float* __restrict__ W1,
    const float* __restrict__ g1, const float* __restrict__ b1,
    const float* __restrict__ m1, const float* __restrict__ v1,
    const float* __restrict__ W2,
    const float* __restrict__ g2, const float* __restrict__ b2,
    const float* __restrict__ m2, const float* __restrict__ v2,
    short* __restrict__ W1p, short* __restrict__ W2p, float* __restrict__ bn)
{
    int blk = blockIdx.x;
    if (blk < TBLK) {
        // ------------- transpose f [B,C,N] fp32 -> fT [B*N][64] bf16 -------
        int g = blk * 256 + threadIdx.x;
        int b = g >> 13, n = g & (N_ - 1);
        const float* fb = f + (size_t)b * C_ * N_ + n;     // coalesced over n
        short* row = fT + (size_t)g * C_;
        #pragma unroll
        for (int c0 = 0; c0 < C_; c0 += 8) {
            float t0 = fb[(size_t)(c0 + 0) * N_], t1 = fb[(size_t)(c0 + 1) * N_];
            float t2 = fb[(size_t)(c0 + 2) * N_], t3 = fb[(size_t)(c0 + 3) * N_];
            float t4 = fb[(size_t)(c0 + 4) * N_], t5 = fb[(size_t)(c0 + 5) * N_];
            float t6 = fb[(size_t)(c0 + 6) * N_], t7 = fb[(size_t)(c0 + 7) * N_];
            union { bf16x8 v; unsigned u[4]; } uu;
            uu.u[0] = cvt_pk_bf16(t0, t1); uu.u[1] = cvt_pk_bf16(t2, t3);
            uu.u[2] = cvt_pk_bf16(t4, t5); uu.u[3] = cvt_pk_bf16(t6, t7);
            *(bf16x8*)&row[c0] = uu.v;
        }
    } else if (blk == TBLK) {
        // ------------- weight / BN prep ------------------------------------
        if (threadIdx.x >= 128) return;
        int t = threadIdx.x;
        short* r1 = W1p + t * KP;     // k 0..2 dp, 3..7 zero, 8..71 f, 72..95 zero
        #pragma unroll
        for (int k = 0; k < 3; ++k) r1[k] = f2bf(W1[t * CIN_ + k]);
        #pragma unroll
        for (int k = 3; k < 8; ++k) r1[k] = 0;
        for (int c = 0; c < 64; ++c) r1[8 + c] = f2bf(W1[t * CIN_ + 3 + c]);
        #pragma unroll
        for (int k = 72; k < KP; ++k) r1[k] = 0;
        short* r2 = W2p + t * C1_;
        for (int c = 0; c < C1_; ++c) r2[c] = f2bf(W2[t * C1_ + c]);
        float s1 = g1[t] * rsqrtf(v1[t] + EPS_);
        bn[t] = s1;            bn[128 + t] = b1[t] - m1[t] * s1;
        float s2 = g2[t] * rsqrtf(v2[t] + EPS_);
        bn[256 + t] = s2;      bn[384 + t] = b2[t] - m2[t] * s2;
    } else {
        // ------------- ball query: wave/point, prefetch 1 chunk ahead ------
        int wid = (blk - QBLK0) * 4 + (threadIdx.x >> 6);   // 0..B*N-1
        int lane = threadIdx.x & 63;
        int b = wid >> 13, n = wid & (N_ - 1);
        const float* pb = p + (size_t)b * N_ * 3;
        float qx = pb[3 * n], qy = pb[3 * n + 1], qz = pb[3 * n + 2];
        int* out = idx + (size_t)wid * NSAMPLE;
        short* dq = dpq + (size_t)wid * NSAMPLE * 4;
        int cnt = 0, first = -1;
        const float* q0 = pb + 12 * lane;
        f32x4 u0 = *(const f32x4*)(q0);
        f32x4 u1 = *(const f32x4*)(q0 + 4);
        f32x4 u2 = *(const f32x4*)(q0 + 8);
        for (int j0 = 0; j0 < N_; j0 += 256) {
            // unconditional prefetch of next chunk (clamped; wasted on last)
            int jn = (j0 + 256 < N_) ? j0 + 256 : 0;
            const float* qn = pb + 3 * (jn + 4 * lane);
            f32x4 w0 = *(const f32x4*)(qn);
            f32x4 w1 = *(const f32x4*)(qn + 4);
            f32x4 w2 = *(const f32x4*)(qn + 8);
            int jb = j0 + 4 * lane;
            float x0 = u0[0], y0 = u0[1], z0 = u0[2];
            float x1 = u0[3], y1 = u1[0], z1 = u1[1];
            float x2 = u1[2], y2 = u1[3], z2 = u2[0];
            float x3 = u2[1], y3 = u2[2], z3 = u2[3];
            // exact-rn arithmetic (no fma contraction) to match reference
            float ax0 = __fadd_rn(x0, -qx), ay0 = __fadd_rn(y0, -qy), az0 = __fadd_rn(z0, -qz);
            float ax1 = __fadd_rn(x1, -qx), ay1 = __fadd_rn(y1, -qy), az1 = __fadd_rn(z1, -qz);
            float ax2 = __fadd_rn(x2, -qx), ay2 = __fadd_rn(y2, -qy), az2 = __fadd_rn(z2, -qz);
            float ax3 = __fadd_rn(x3, -qx), ay3 = __fadd_rn(y3, -qy), az3 = __fadd_rn(z3, -qz);
            float d20 = __fadd_rn(__fadd_rn(__fmul_rn(ax0, ax0), __fmul_rn(ay0, ay0)), __fmul_rn(az0, az0));
            float d21 = __fadd_rn(__fadd_rn(__fmul_rn(ax1, ax1), __fmul_rn(ay1, ay1)), __fmul_rn(az1, az1));
            float d22 = __fadd_rn(__fadd_rn(__fmul_rn(ax2, ax2), __fmul_rn(ay2, ay2)), __fmul_rn(az2, az2));
            float d23 = __fadd_rn(__fadd_rn(__fmul_rn(ax3, ax3), __fmul_rn(ay3, ay3)), __fmul_rn(az3, az3));
            bool h0 = d20 < BQ_R2, h1 = d21 < BQ_R2, h2 = d22 < BQ_R2, h3 = d23 < BQ_R2;
            ull m0 = __ballot(h0), m1 = __ballot(h1);
            ull m2 = __ballot(h2), m3 = __ballot(h3);
            ull below = (1ull << lane) - 1ull;
            int pos = cnt + __popcll(m0 & below) + __popcll(m1 & below)
                          + __popcll(m2 & below) + __popcll(m3 & below);
            if (h0) { if (pos < NSAMPLE) { out[pos] = jb;
                ull dv = (ull)cvt_pk_bf16(ax0, ay0) | ((ull)cvt_pk_bf16(az0, 0.f) << 32);
                *(ull*)&dq[pos * 4] = dv; } ++pos; }
            if (h1) { if (pos < NSAMPLE) { out[pos] = jb + 1;
                ull dv = (ull)cvt_pk_bf16(ax1, ay1) | ((ull)cvt_pk_bf16(az1, 0.f) << 32);
                *(ull*)&dq[pos * 4] = dv; } ++pos; }
            if (h2) { if (pos < NSAMPLE) { out[pos] = jb + 2;
                ull dv = (ull)cvt_pk_bf16(ax2, ay2) | ((ull)cvt_pk_bf16(az2, 0.f) << 32);
                *(ull*)&dq[pos * 4] = dv; } ++pos; }
            if (h3) { if (pos < NSAMPLE) { out[pos] = jb + 3;
                ull dv = (ull)cvt_pk_bf16(ax3, ay3) | ((ull)cvt_pk_bf16(az3, 0.f) << 32);
                *(ull*)&dq[pos * 4] = dv; } ++pos; }
            if (first < 0) {
                int fj = 0x7fffffff;
                if (m0) fj = min(fj, 4 * (__ffsll((long long)m0) - 1));
                if (m1) fj = min(fj, 4 * (__ffsll((long long)m1) - 1) + 1);
                if (m2) fj = min(fj, 4 * (__ffsll((long long)m2) - 1) + 2);
                if (m3) fj = min(fj, 4 * (__ffsll((long long)m3) - 1) + 3);
                if (fj != 0x7fffffff) first = j0 + fj;
            }
            cnt += __popcll(m0) + __popcll(m1) + __popcll(m2) + __popcll(m3);
            u0 = w0; u1 = w1; u2 = w2;
            if (cnt >= NSAMPLE) break;              // wave-uniform
        }
        // padding: idx = first hit; dp = p[first] - p[n]
        float fx = __fadd_rn(pb[3 * first],     -qx);
        float fy = __fadd_rn(pb[3 * first + 1], -qy);
        float fz = __fadd_rn(pb[3 * first + 2], -qz);
        ull fdv = (ull)cvt_pk_bf16(fx, fy) | ((ull)cvt_pk_bf16(fz, 0.f) << 32);
        for (int k2 = cnt + lane; k2 < NSAMPLE; k2 += 64) {
            out[k2] = first;
            *(ull*)&dq[k2 * 4] = fdv;
        }
    }
}

// ---- fused: gather + GEMM1+BN/ReLU + GEMM2+BN + max -----------------------
// Block: 256 thr (4 waves), 4 points (128 cols). Wave w: rows (w&1)*64,
// cols (w>>1)*64. LDS: one [128 col][16 slot][8 short] buffer (256B rows),
// XOR-swizzled slot ^= col&7 (bank-conflict-minimal b128), XT/HT phased.
__global__ __launch_bounds__(256) void fused_mfma_kernel(
    const int* __restrict__ idx, const short* __restrict__ dpq,
    const short* __restrict__ fT, const short* __restrict__ W1p,
    const short* __restrict__ W2p, const float* __restrict__ bn,
    float* __restrict__ out)
{
    __shared__ short smem[128 * 128];    // 32 KB
    __shared__ int sidx[128];

    int tid = threadIdx.x;
    int bk = blockIdx.x;
    bk = (bk & 7) * 512 + (bk >> 3);     // XCD-contiguous swizzle (4096 = 8*512)
    int b = bk >> 11;
    int n0 = (bk & 2047) * 4;
    int lane = tid & 63, w = tid >> 6;
    int lr = lane & 15, lq = lane >> 4;
    int wr = (w & 1) * 64;               // row (out-channel) base
    int wc = (w >> 1) * 64;              // col (sample) base

    if (tid < 128)
        sidx[tid] = idx[((size_t)((b << 13) + n0)) * NSAMPLE + tid];

    // hoist GEMM1 A-fragments (global, overlaps sidx/staging latency)
    bf16x8 a1[3][4];
    #pragma unroll
    for (int ks = 0; ks < 3; ++ks)
        #pragma unroll
        for (int m = 0; m < 4; ++m)
            a1[ks][m] = *(const bf16x8*)&W1p[(wr + m * 16 + lr) * KP + ks * 32 + lq * 8];
    __syncthreads();

    // ---- stage XT: 8 threads per column; logical slots 0..11 ----
    #pragma unroll
    for (int pass = 0; pass < 4; ++pass) {
        int col = pass * 32 + (tid >> 3);
        int part = tid & 7;
        int c7 = col & 7;
        int j = sidx[col];
        *(bf16x8*)&smem[col * 128 + (((1 + part) ^ c7) << 3)] =
            *(const bf16x8*)&fT[((size_t)(b << 13) + j) * C_ + part * 8];
        if (part == 0) {                 // slot 0: dp + zeros
            ull dv = *(const ull*)&dpq[((size_t)((b << 13) + n0 + pass) * NSAMPLE
                                        + (col & 31)) * 4];
            union { bf16x8 v; ull q[2]; } uu;
            uu.q[0] = dv; uu.q[1] = 0;
            *(bf16x8*)&smem[col * 128 + ((0 ^ c7) << 3)] = uu.v;
        } else if (part <= 3) {          // slots 9..11: zero pad (k 72..95)
            bf16x8 z = {0, 0, 0, 0, 0, 0, 0, 0};
            *(bf16x8*)&smem[col * 128 + (((8 + part) ^ c7) << 3)] = z;
        }
    }
    __syncthreads();

    // ---- GEMM1: [128x96] x [96x128] ----
    f32x4 acc[4][4];
    #pragma unroll
    for (int m = 0; m < 4; ++m)
        #pragma unroll
        for (int nt = 0; nt < 4; ++nt) acc[m][nt] = (f32x4){0.f, 0.f, 0.f, 0.f};
    #pragma unroll
    for (int ks = 0; ks < 3; ++ks)
        #pragma unroll
        for (int nt = 0; nt < 4; ++nt) {
            int col = wc + nt * 16 + lr;
            bf16x8 bf = *(const bf16x8*)&smem[col * 128 + ((((ks << 2) + lq) ^ (col & 7)) << 3)];
            #pragma unroll
            for (int m = 0; m < 4; ++m)
                acc[m][nt] = __builtin_amdgcn_mfma_f32_16x16x32_bf16(a1[ks][m], bf, acc[m][nt], 0, 0, 0);
        }
    __syncthreads();          // all XT reads done before HT overwrites

    // ---- BN1 + ReLU -> HT (bf16, [col][c]) ----
    #pragma unroll
    for (int m = 0; m < 4; ++m) {
        int rb = wr + m * 16 + lq * 4;
        f32x4 sc = *(const f32x4*)&bn[rb];
        f32x4 sh = *(const f32x4*)&bn[128 + rb];
        #pragma unroll
        for (int nt = 0; nt < 4; ++nt) {
            int col = wc + nt * 16 + lr;
            float y0 = fmaxf(fmaf(acc[m][nt][0], sc[0], sh[0]), 0.f);
            float y1 = fmaxf(fmaf(acc[m][nt][1], sc[1], sh[1]), 0.f);
            float y2 = fmaxf(fmaf(acc[m][nt][2], sc[2], sh[2]), 0.f);
            float y3 = fmaxf(fmaf(acc[m][nt][3], sc[3], sh[3]), 0.f);
            ull dv = (ull)cvt_pk_bf16(y0, y1) | ((ull)cvt_pk_bf16(y2, y3) << 32);
            *(ull*)&smem[col * 128 + ((((rb >> 3) ^ (col & 7)) << 3) | (rb & 7))] = dv;
        }
    }
    __syncthreads();

    // ---- GEMM2: [128x128] x [128x128] ----
    f32x4 acc2[4][4];
    #pragma unroll
    for (int m = 0; m < 4; ++m)
        #pragma unroll
        for (int nt = 0; nt < 4; ++nt) acc2[m][nt] = (f32x4){0.f, 0.f, 0.f, 0.f};
    #pragma unroll
    for (int ks = 0; ks < 4; ++ks) {
        bf16x8 a2[4];
        #pragma unroll
        for (int m = 0; m < 4; ++m)
            a2[m] = *(const bf16x8*)&W2p[(wr + m * 16 + lr) * C1_ + ks * 32 + lq * 8];
        #pragma unroll
        for (int nt = 0; nt < 4; ++nt) {
            int col = wc + nt * 16 + lr;
            bf16x8 bf = *(const bf16x8*)&smem[col * 128 + ((((ks << 2) + lq) ^ (col & 7)) << 3)];
            #pragma unroll
            for (int m = 0; m < 4; ++m)
                acc2[m][nt] = __builtin_amdgcn_mfma_f32_16x16x32_bf16(a2[m], bf, acc2[m][nt], 0, 0, 0);
        }
    }

    // ---- BN2 + max over k + ReLU + store ----
    #pragma unroll
    for (int m = 0; m < 4; ++m) {
        int rb = wr + m * 16 + lq * 4;
        f32x4 sc = *(const f32x4*)&bn[256 + rb];
        f32x4 sh = *(const f32x4*)&bn[384 + rb];
        #pragma unroll
        for (int lp = 0; lp < 2; ++lp) {       // 2 points per wave
            int n = n0 + (w >> 1) * 2 + lp;
            float v0 = fmaxf(fmaf(acc2[m][2 * lp][0], sc[0], sh[0]), fmaf(acc2[m][2 * lp + 1][0], sc[0], sh[0]));
            float v1 = fmaxf(fmaf(acc2[m][2 * lp][1], sc[1], sh[1]), fmaf(acc2[m][2 * lp + 1][1], sc[1], sh[1]));
            float v2 = fmaxf(fmaf(acc2[m][2 * lp][2], sc[2], sh[2]), fmaf(acc2[m][2 * lp + 1][2], sc[2], sh[2]));
            float v3 = fmaxf(fmaf(acc2[m][2 * lp][3], sc[3], sh[3]), fmaf(acc2[m][2 * lp + 1][3], sc[3], sh[3]));
            #pragma unroll
            for (int st = 1; st <= 8; st <<= 1) {
                v0 = fmaxf(v0, __shfl_xor(v0, st, 64));
                v1 = fmaxf(v1, __shfl_xor(v1, st, 64));
                v2 = fmaxf(v2, __shfl_xor(v2, st, 64));
                v3 = fmaxf(v3, __shfl_xor(v3, st, 64));
            }
            if (lr == 0) {
                out[((size_t)(b * C2_ + rb))     * N_ + n] = fmaxf(v0, 0.f);
                out[((size_t)(b * C2_ + rb + 1)) * N_ + n] = fmaxf(v1, 0.f);
                out[((size_t)(b * C2_ + rb + 2)) * N_ + n] = fmaxf(v2, 0.f);
                out[((size_t)(b * C2_ + rb + 3)) * N_ + n] = fmaxf(v3, 0.f);
            }
        }
    }
}

extern "C" void kernel_launch(void* const* d_in, const int* in_sizes, int n_in,
                              void* d_out, int out_size, void* d_ws, size_t ws_size,
                              hipStream_t stream) {
    const float* p   = (const float*)d_in[0];
    const float* f   = (const float*)d_in[1];
    const float* W1  = (const float*)d_in[2];
    const float* g1  = (const float*)d_in[3];
    const float* bb1 = (const float*)d_in[4];
    const float* m1  = (const float*)d_in[5];
    const float* v1  = (const float*)d_in[6];
    const float* W2  = (const float*)d_in[7];
    const float* g2  = (const float*)d_in[8];
    const float* bb2 = (const float*)d_in[9];
    const float* m2  = (const float*)d_in[10];
    const float* v2  = (const float*)d_in[11];
    float* out = (float*)d_out;

    char* ws = (char*)d_ws;
    int*   idxbuf = (int*)ws;                         // 2 MB
    short* dpq = (short*)(ws + (2 << 20));            // 4 MB
    short* fT  = (short*)(ws + (6 << 20));            // 2 MB
    short* W1p = (short*)(ws + (8 << 20));            // 24 KB
    short* W2p = (short*)(ws + (8 << 20) + 0x6000);   // 32 KB
    float* bnv = (float*)(ws + (8 << 20) + 0xE000);   // 2 KB

    prep_query_kernel<<<QBLK0 + (B_ * N_) / 4, 256, 0, stream>>>(
        p, f, fT, idxbuf, dpq, W1, g1, bb1, m1, v1, W2, g2, bb2, m2, v2,
        W1p, W2p, bnv);
    fused_mfma_kernel<<<(B_ * N_) / 4, 256, 0, stream>>>(
        idxbuf, dpq, fT, W1p, W2p, bnv, out);
}